// Round 3
// baseline (3398.145 us; speedup 1.0000x reference)
//
#include <hip/hip_runtime.h>
#include <cstdint>
#include <cstddef>

#define BATCH 4096
#define DIM 64
#define HID 512
#define NPER 2048
#define KEV 25
#define DT_C 0.01f
#define LOG_SQRT_2PI_C 0.9189385332046727f

typedef __attribute__((ext_vector_type(8))) short short8;
typedef __attribute__((ext_vector_type(4))) float f32x4;

__device__ __forceinline__ ushort f2bf(float f) {
    uint32_t u = __float_as_uint(f);
    u += 0x7FFF + ((u >> 16) & 1);
    return (ushort)(u >> 16);
}
__device__ __forceinline__ float sigmoidf_(float x) { return 1.0f / (1.0f + expf(-x)); }

__device__ __forceinline__ void gload_lds16(const ushort* g, ushort* l) {
    __builtin_amdgcn_global_load_lds(
        (const __attribute__((address_space(1))) void*)g,
        (__attribute__((address_space(3))) void*)l, 16, 0, 0);
}

// fragment read from a [rows][64]-elem LDS tile, XOR-swizzled in 8-elem slots
__device__ __forceinline__ short8 frag64(const ushort* lds, int row, int ks, int lane) {
    int slot = ((ks << 2) + (lane >> 4)) ^ (row & 7);
    return *(const short8*)&lds[row * 64 + slot * 8];
}

// ---------------- fused Euler step: h += DT*(tanh(h W1^T + b1) W2^T + b2) ----
// grid 128 blocks x 256 thr (4 waves). Block: 32 rows, all 512 cols.
__global__ __launch_bounds__(256, 1) void ode_step(
    const float* __restrict__ b1, const float* __restrict__ b2,
    const ushort* __restrict__ W1, const ushort* __restrict__ W2,
    float* __restrict__ h, ushort* __restrict__ hb)
{
    __shared__ __align__(16) ushort Alds[32 * HID];   // 32 KB
    __shared__ __align__(16) ushort Wlds[HID * 64];   // 64 KB
    __shared__ __align__(16) ushort Tlds[32 * HID];   // 32 KB
    const int tid = threadIdx.x, lane = tid & 63, w = tid >> 6;
    const int r0 = blockIdx.x * 32;

    // stage A = hb rows r0..r0+31, full K=512 (one row per gload: 64 lanes x 16B)
    #pragma unroll
    for (int i = 0; i < 8; ++i) {
        int r = w * 8 + i;
        gload_lds16(hb + (size_t)(r0 + r) * HID + ((lane ^ (r & 7)) << 3), &Alds[r * HID]);
    }

    f32x4 acc[2][8];
    const ushort* Wp = W1;
    for (int phase = 0; phase < 2; ++phase) {
        #pragma unroll
        for (int mi = 0; mi < 2; ++mi)
            #pragma unroll
            for (int ni = 0; ni < 8; ++ni) acc[mi][ni] = (f32x4){0.f, 0.f, 0.f, 0.f};
        const ushort* Asrc = (phase == 0) ? Alds : Tlds;

        for (int k0 = 0; k0 < HID; k0 += 64) {
            // stage W panel: 512 rows x 64 k  (16 gloads/wave, 8 rows each)
            #pragma unroll
            for (int i = 0; i < 16; ++i) {
                int g = w * 16 + i;
                int rw = g * 8 + (lane >> 3);
                gload_lds16(Wp + (size_t)rw * HID + k0 + (((lane & 7) ^ (rw & 7)) << 3),
                            &Wlds[g * 8 * 64]);
            }
            __syncthreads();
            short8 af[2][2], bw[8][2];
            #pragma unroll
            for (int mi = 0; mi < 2; ++mi) {
                int r = mi * 16 + (lane & 15);
                #pragma unroll
                for (int ks = 0; ks < 2; ++ks) {
                    int q = (k0 >> 3) + (ks << 2) + (lane >> 4);
                    af[mi][ks] = *(const short8*)&Asrc[r * HID + ((q ^ (r & 7)) << 3)];
                }
            }
            #pragma unroll
            for (int ni = 0; ni < 8; ++ni) {
                int c = w * 128 + ni * 16 + (lane & 15);
                #pragma unroll
                for (int ks = 0; ks < 2; ++ks)
                    bw[ni][ks] = frag64(Wlds, c, ks, lane);
            }
            #pragma unroll
            for (int ks = 0; ks < 2; ++ks)
                #pragma unroll
                for (int mi = 0; mi < 2; ++mi)
                    #pragma unroll
                    for (int ni = 0; ni < 8; ++ni)
                        acc[mi][ni] = __builtin_amdgcn_mfma_f32_16x16x32_bf16(
                            af[mi][ks], bw[ni][ks], acc[mi][ni], 0, 0, 0);
            __syncthreads();
        }

        if (phase == 0) {
            // t = tanh(acc + b1) -> Tlds (bf16, swizzled); visible after next barrier
            #pragma unroll
            for (int mi = 0; mi < 2; ++mi)
                #pragma unroll
                for (int ni = 0; ni < 8; ++ni) {
                    int c = w * 128 + ni * 16 + (lane & 15);
                    float bv = b1[c];
                    #pragma unroll
                    for (int ii = 0; ii < 4; ++ii) {
                        int r = mi * 16 + ((lane >> 4) << 2) + ii;
                        float t = tanhf(acc[mi][ni][ii] + bv);
                        Tlds[r * HID + ((((c >> 3) ^ (r & 7)) << 3) + (c & 7))] = f2bf(t);
                    }
                }
            Wp = W2;
        } else {
            #pragma unroll
            for (int mi = 0; mi < 2; ++mi)
                #pragma unroll
                for (int ni = 0; ni < 8; ++ni) {
                    int c = w * 128 + ni * 16 + (lane & 15);
                    float bv = b2[c];
                    #pragma unroll
                    for (int ii = 0; ii < 4; ++ii) {
                        int r = r0 + mi * 16 + ((lane >> 4) << 2) + ii;
                        size_t o = (size_t)r * HID + c;
                        float hn = h[o] + DT_C * (acc[mi][ni][ii] + bv);
                        h[o] = hn; hb[o] = f2bf(hn);
                    }
                }
        }
    }
}

// ---------------- event GEMM: A rows gathered from hb[idx], optional K=64 tail
// MODE 0: q = relu(hg Wp1^T + bp1)            -> qb bf16    (no tail)
// MODE 1: rz = sigmoid(concatK + b_ih + b_hh) -> rz fp32    (tail into acc)
// MODE 2: GRU n-gate + combine + scatter to h (tail into accX)
template<int MODE>
__global__ __launch_bounds__(256) void event_gemm(
    const ushort* __restrict__ hb, const ushort* __restrict__ Xbk,
    const int* __restrict__ idx,
    const ushort* __restrict__ Bh, const ushort* __restrict__ Bx,
    const float* __restrict__ bias_i, const float* __restrict__ bias_h,
    float* __restrict__ rz, ushort* __restrict__ qb, float* __restrict__ h)
{
    __shared__ __align__(16) ushort Alds[64 * 64];
    __shared__ __align__(16) ushort Blds[64 * 64];
    const int tid = threadIdx.x, lane = tid & 63, w = tid >> 6;
    const int wr = w >> 1, wc = w & 1;
    const int r0t = blockIdx.y * 64;
    const int c0t = blockIdx.x * 64;

    f32x4 acc[2][2] = {};
    f32x4 accX[2][2] = {};

    const int arow = w * 16 + (lane >> 3);                    // staged row (cc=0)
    const int sg   = ((lane & 7) ^ ((lane >> 3) & 7)) << 3;   // swizzled 8-elem slot
    const int gidx0 = idx[r0t + arow];
    const int gidx1 = idx[r0t + arow + 8];

    for (int k0 = 0; k0 < HID; k0 += 64) {
        __syncthreads();
        gload_lds16(hb + (size_t)gidx0 * HID + k0 + sg, &Alds[(w * 16) * 64]);
        gload_lds16(hb + (size_t)gidx1 * HID + k0 + sg, &Alds[(w * 16 + 8) * 64]);
        gload_lds16(Bh + (size_t)(c0t + arow) * HID + k0 + sg, &Blds[(w * 16) * 64]);
        gload_lds16(Bh + (size_t)(c0t + arow + 8) * HID + k0 + sg, &Blds[(w * 16 + 8) * 64]);
        __syncthreads();
        short8 af[2][2], bf[2][2];
        #pragma unroll
        for (int mi = 0; mi < 2; ++mi) {
            int r = wr * 32 + mi * 16 + (lane & 15);
            #pragma unroll
            for (int ks = 0; ks < 2; ++ks) af[mi][ks] = frag64(Alds, r, ks, lane);
        }
        #pragma unroll
        for (int ni = 0; ni < 2; ++ni) {
            int c = wc * 32 + ni * 16 + (lane & 15);
            #pragma unroll
            for (int ks = 0; ks < 2; ++ks) bf[ni][ks] = frag64(Blds, c, ks, lane);
        }
        #pragma unroll
        for (int ks = 0; ks < 2; ++ks)
            #pragma unroll
            for (int mi = 0; mi < 2; ++mi)
                #pragma unroll
                for (int ni = 0; ni < 2; ++ni)
                    acc[mi][ni] = __builtin_amdgcn_mfma_f32_16x16x32_bf16(
                        af[mi][ks], bf[ni][ks], acc[mi][ni], 0, 0, 0);
    }

    if (MODE != 0) {   // K tail: A from Xbk (stride 64), B from Bx (stride 64)
        __syncthreads();
        gload_lds16(Xbk + (size_t)(r0t + arow) * DIM + sg, &Alds[(w * 16) * 64]);
        gload_lds16(Xbk + (size_t)(r0t + arow + 8) * DIM + sg, &Alds[(w * 16 + 8) * 64]);
        gload_lds16(Bx + (size_t)(c0t + arow) * DIM + sg, &Blds[(w * 16) * 64]);
        gload_lds16(Bx + (size_t)(c0t + arow + 8) * DIM + sg, &Blds[(w * 16 + 8) * 64]);
        __syncthreads();
        short8 af[2][2], bf[2][2];
        #pragma unroll
        for (int mi = 0; mi < 2; ++mi) {
            int r = wr * 32 + mi * 16 + (lane & 15);
            #pragma unroll
            for (int ks = 0; ks < 2; ++ks) af[mi][ks] = frag64(Alds, r, ks, lane);
        }
        #pragma unroll
        for (int ni = 0; ni < 2; ++ni) {
            int c = wc * 32 + ni * 16 + (lane & 15);
            #pragma unroll
            for (int ks = 0; ks < 2; ++ks) bf[ni][ks] = frag64(Blds, c, ks, lane);
        }
        #pragma unroll
        for (int ks = 0; ks < 2; ++ks)
            #pragma unroll
            for (int mi = 0; mi < 2; ++mi)
                #pragma unroll
                for (int ni = 0; ni < 2; ++ni) {
                    f32x4& a = (MODE == 2) ? accX[mi][ni] : acc[mi][ni];
                    a = __builtin_amdgcn_mfma_f32_16x16x32_bf16(
                        af[mi][ks], bf[ni][ks], a, 0, 0, 0);
                }
    }

    #pragma unroll
    for (int mi = 0; mi < 2; ++mi)
        #pragma unroll
        for (int ni = 0; ni < 2; ++ni) {
            const int c = c0t + wc * 32 + ni * 16 + (lane & 15);
            #pragma unroll
            for (int ii = 0; ii < 4; ++ii) {
                const int iobs = r0t + wr * 32 + mi * 16 + ((lane >> 4) << 2) + ii;
                float v = acc[mi][ni][ii];
                if (MODE == 0) {
                    qb[(size_t)iobs * HID + c] = f2bf(fmaxf(v + bias_h[c], 0.0f));
                } else if (MODE == 1) {
                    rz[(size_t)iobs * 1024 + c] = sigmoidf_(v + bias_i[c] + bias_h[c]);
                } else {
                    float vh = v + bias_h[c];
                    float vx = accX[mi][ni][ii] + bias_i[c];
                    float r = rz[(size_t)iobs * 1024 + c];
                    float z = rz[(size_t)iobs * 1024 + 512 + c];
                    float n = tanhf(vx + r * vh);
                    size_t o = (size_t)idx[iobs] * HID + c;
                    h[o] = (1.0f - z) * n + z * h[o];
                }
            }
        }
}

// refresh bf16 shadow of updated rows (after MODE 2)
__global__ __launch_bounds__(256) void scatter_b16(
    const float* __restrict__ h, const int* __restrict__ idx, ushort* __restrict__ hb)
{
    int t = blockIdx.x * 256 + threadIdx.x;   // over NPER*HID/8
    int i = t >> 6, j8 = (t & 63) << 3;
    size_t o = (size_t)idx[i] * HID + j8;
    float4 a = *(const float4*)&h[o];
    float4 b = *(const float4*)&h[o + 4];
    ushort ob[8] = {f2bf(a.x), f2bf(a.y), f2bf(a.z), f2bf(a.w),
                    f2bf(b.x), f2bf(b.y), f2bf(b.z), f2bf(b.w)};
    *(ushort4*)&hb[o]     = *(ushort4*)&ob[0];
    *(ushort4*)&hb[o + 4] = *(ushort4*)&ob[4];
}

__device__ __forceinline__ void block_atomic_sum(float v, float* acc) {
    __shared__ float red[4];
    #pragma unroll
    for (int off = 32; off > 0; off >>= 1) v += __shfl_down(v, off);
    int lane = threadIdx.x & 63, wid = threadIdx.x >> 6;
    if (lane == 0) red[wid] = v;
    __syncthreads();
    if (threadIdx.x == 0) atomicAdd(acc, red[0] + red[1] + red[2] + red[3]);
}

// ---------------- p = q Wp2^T + bp2 fused with NLL loss reduce ----------------
// grid 32 blocks x 256 thr; block: 64 rows x all 128 cols
__global__ __launch_bounds__(256) void p_loss(
    const ushort* __restrict__ qb, const ushort* __restrict__ Wp2b,
    const float* __restrict__ bp2, const float* __restrict__ Xk,
    const float* __restrict__ Mk, float* __restrict__ loss_acc)
{
    __shared__ __align__(16) ushort Alds[64 * 64];
    __shared__ __align__(16) ushort Blds[128 * 64];
    __shared__ float Plds[64 * 128];
    const int tid = threadIdx.x, lane = tid & 63, w = tid >> 6;
    const int wr = w >> 1, wc = w & 1;
    const int r0t = blockIdx.x * 64;
    const int arow = w * 16 + (lane >> 3);
    const int sg   = ((lane & 7) ^ ((lane >> 3) & 7)) << 3;

    f32x4 acc[2][4] = {};
    for (int k0 = 0; k0 < HID; k0 += 64) {
        __syncthreads();
        gload_lds16(qb + (size_t)(r0t + arow) * HID + k0 + sg, &Alds[(w * 16) * 64]);
        gload_lds16(qb + (size_t)(r0t + arow + 8) * HID + k0 + sg, &Alds[(w * 16 + 8) * 64]);
        #pragma unroll
        for (int j = 0; j < 4; ++j) {
            int g = w * 4 + j;
            int rw = g * 8 + (lane >> 3);
            gload_lds16(Wp2b + (size_t)rw * HID + k0 + (((lane & 7) ^ (rw & 7)) << 3),
                        &Blds[g * 8 * 64]);
        }
        __syncthreads();
        short8 af[2][2], bf[4][2];
        #pragma unroll
        for (int mi = 0; mi < 2; ++mi) {
            int r = wr * 32 + mi * 16 + (lane & 15);
            #pragma unroll
            for (int ks = 0; ks < 2; ++ks) af[mi][ks] = frag64(Alds, r, ks, lane);
        }
        #pragma unroll
        for (int ni = 0; ni < 4; ++ni) {
            int c = wc * 64 + ni * 16 + (lane & 15);
            #pragma unroll
            for (int ks = 0; ks < 2; ++ks) bf[ni][ks] = frag64(Blds, c, ks, lane);
        }
        #pragma unroll
        for (int ks = 0; ks < 2; ++ks)
            #pragma unroll
            for (int mi = 0; mi < 2; ++mi)
                #pragma unroll
                for (int ni = 0; ni < 4; ++ni)
                    acc[mi][ni] = __builtin_amdgcn_mfma_f32_16x16x32_bf16(
                        af[mi][ks], bf[ni][ks], acc[mi][ni], 0, 0, 0);
    }

    #pragma unroll
    for (int mi = 0; mi < 2; ++mi)
        #pragma unroll
        for (int ni = 0; ni < 4; ++ni) {
            int c = wc * 64 + ni * 16 + (lane & 15);
            float bv = bp2[c];
            #pragma unroll
            for (int ii = 0; ii < 4; ++ii) {
                int r = wr * 32 + mi * 16 + ((lane >> 4) << 2) + ii;
                Plds[r * 128 + c] = acc[mi][ni][ii] + bv;
            }
        }
    __syncthreads();

    float local = 0.0f;
    for (int t = tid; t < 64 * 64; t += 256) {
        int r = t >> 6, j = t & 63;
        float mean = Plds[r * 128 + j];
        float lv   = Plds[r * 128 + 64 + j];
        int g = r0t + r;
        float err = (Xk[g * 64 + j] - mean) * expf(-0.5f * lv);
        local += 0.5f * (err * err + lv + 2.0f * LOG_SQRT_2PI_C) * Mk[g * 64 + j];
    }
    block_atomic_sum(local, loss_acc);
}

__global__ __launch_bounds__(256) void f2b4_kernel(
    const float* __restrict__ s, ushort* __restrict__ d, int n4)
{
    int t = blockIdx.x * 256 + threadIdx.x;
    if (t >= n4) return;
    float4 v = ((const float4*)s)[t];
    ushort4 o; o.x = f2bf(v.x); o.y = f2bf(v.y); o.z = f2bf(v.z); o.w = f2bf(v.w);
    ((ushort4*)d)[t] = o;
}

__global__ __launch_bounds__(256) void msum_kernel(
    const float* __restrict__ M, int n, float* __restrict__ m_acc)
{
    float v = 0.0f;
    for (int t = blockIdx.x * 256 + threadIdx.x; t < n; t += gridDim.x * 256)
        v += M[t];
    block_atomic_sum(v, m_acc);
}

__global__ void finalize_kernel(const float* __restrict__ sums, float* __restrict__ out) {
    if (threadIdx.x == 0) { out[0] = sums[0] / sums[1]; out[1] = 0.0f; }
}

extern "C" void kernel_launch(void* const* d_in, const int* in_sizes, int n_in,
                              void* d_out, int out_size, void* d_ws, size_t ws_size,
                              hipStream_t stream) {
    const float* X      = (const float*)d_in[3];
    const float* M      = (const float*)d_in[4];
    const int* batch_idx= (const int*)  d_in[5];
    const float* W_ode1 = (const float*)d_in[6];
    const float* b_ode1 = (const float*)d_in[7];
    const float* W_ode2 = (const float*)d_in[8];
    const float* b_ode2 = (const float*)d_in[9];
    const float* W_ih   = (const float*)d_in[10];
    const float* W_hh   = (const float*)d_in[11];
    const float* b_ih   = (const float*)d_in[12];
    const float* b_hh   = (const float*)d_in[13];
    const float* Wp1    = (const float*)d_in[14];
    const float* bp1    = (const float*)d_in[15];
    const float* Wp2    = (const float*)d_in[16];
    const float* bp2    = (const float*)d_in[17];
    float* out = (float*)d_out;

    float* ws   = (float*)d_ws;
    float* h    = ws;                                   // 4096*512
    float* rz   = h  + (size_t)BATCH * HID;             // 2048*1024
    float* sums = rz + (size_t)NPER * 1024;             // 16
    ushort* hb   = (ushort*)(sums + 16);                // 4096*512
    ushort* qb   = hb   + (size_t)BATCH * HID;          // 2048*512
    ushort* Xb   = qb   + (size_t)NPER * HID;           // 25*2048*64
    ushort* W1b  = Xb   + (size_t)KEV * NPER * DIM;     // 512*512
    ushort* W2b  = W1b  + (size_t)HID * HID;
    ushort* Wp1b = W2b  + (size_t)HID * HID;
    ushort* Wp2b = Wp1b + (size_t)HID * HID;            // 128*512
    ushort* Wihb = Wp2b + (size_t)2 * DIM * HID;        // 1536*64
    ushort* Whhb = Wihb + (size_t)(3 * HID) * DIM;      // 1536*512

    hipMemsetAsync(h,    0, (size_t)BATCH * HID * sizeof(float), stream);
    hipMemsetAsync(hb,   0, (size_t)BATCH * HID * sizeof(ushort), stream);
    hipMemsetAsync(sums, 0, 2 * sizeof(float), stream);

    dim3 blk(256);
    auto cvt = [&](const float* s, ushort* d, size_t n) {
        f2b4_kernel<<<dim3((unsigned)((n / 4 + 255) / 256)), blk, 0, stream>>>(s, d, (int)(n / 4));
    };
    cvt(W_ode1, W1b,  (size_t)HID * HID);
    cvt(W_ode2, W2b,  (size_t)HID * HID);
    cvt(Wp1,    Wp1b, (size_t)HID * HID);
    cvt(Wp2,    Wp2b, (size_t)2 * DIM * HID);
    cvt(W_ih,   Wihb, (size_t)3 * HID * DIM);
    cvt(W_hh,   Whhb, (size_t)3 * HID * HID);
    cvt(X,      Xb,   (size_t)KEV * NPER * DIM);

    msum_kernel<<<1024, blk, 0, stream>>>(M, KEV * NPER * DIM, sums + 1);

    for (int k = 0; k < KEV; ++k) {
        const float*  Xk  = X  + (size_t)k * NPER * DIM;
        const float*  Mk  = M  + (size_t)k * NPER * DIM;
        const ushort* Xbk = Xb + (size_t)k * NPER * DIM;
        const int*   idxk = batch_idx + (size_t)k * NPER;

        ode_step<<<BATCH / 32, blk, 0, stream>>>(b_ode1, b_ode2, W1b, W2b, h, hb);
        ode_step<<<BATCH / 32, blk, 0, stream>>>(b_ode1, b_ode2, W1b, W2b, h, hb);

        // head: q = relu(hg Wp1^T + bp1); then p+loss fused
        event_gemm<0><<<dim3(8, 32), blk, 0, stream>>>(
            hb, nullptr, idxk, Wp1b, nullptr, nullptr, bp1, nullptr, qb, nullptr);
        p_loss<<<32, blk, 0, stream>>>(qb, Wp2b, bp2, Xk, Mk, sums);

        // GRU: rz (concat-K), then n-gate + combine + scatter, then bf16 refresh
        event_gemm<1><<<dim3(16, 32), blk, 0, stream>>>(
            hb, Xbk, idxk, Whhb, Wihb, b_ih, b_hh, rz, nullptr, nullptr);
        event_gemm<2><<<dim3(8, 32), blk, 0, stream>>>(
            hb, Xbk, idxk, Whhb + (size_t)1024 * HID, Wihb + (size_t)1024 * DIM,
            b_ih + 1024, b_hh + 1024, rz, nullptr, h);
        scatter_b16<<<NPER * HID / 8 / 256, blk, 0, stream>>>(h, idxk, hb);
    }

    finalize_kernel<<<1, 64, 0, stream>>>(sums, out);
}

// Round 4
// 2863.052 us; speedup vs baseline: 1.1869x; 1.1869x over previous
//
#include <hip/hip_runtime.h>
#include <cstdint>
#include <cstddef>

#define BATCH 4096
#define DIM 64
#define HID 512
#define NPER 2048
#define KEV 25
#define DT_C 0.01f
#define LOG_SQRT_2PI_C 0.9189385332046727f

typedef __attribute__((ext_vector_type(8))) short short8;
typedef __attribute__((ext_vector_type(4))) float f32x4;

__device__ __forceinline__ ushort f2bf(float f) {
    uint32_t u = __float_as_uint(f);
    u += 0x7FFF + ((u >> 16) & 1);
    return (ushort)(u >> 16);
}
__device__ __forceinline__ float sigmoidf_(float x) { return 1.0f / (1.0f + expf(-x)); }

__device__ __forceinline__ void gload_lds16(const ushort* g, ushort* l) {
    __builtin_amdgcn_global_load_lds(
        (const __attribute__((address_space(1))) void*)g,
        (__attribute__((address_space(3))) void*)l, 16, 0, 0);
}

// fragment read from a [rows][64]-elem LDS tile, XOR-swizzled in 8-elem slots
__device__ __forceinline__ short8 frag64(const ushort* lds, int row, int ks, int lane) {
    int slot = ((ks << 2) + (lane >> 4)) ^ (row & 7);
    return *(const short8*)&lds[row * 64 + slot * 8];
}

// ---------------- ODE GEMM: C = A @ W^T, 128x64 tile, dbuf LDS pipeline -----
// MODE 0: Cb = bf16(tanh(v + bias))
// MODE 1: h += DT*(v + bias) (fp32 master), Cb = bf16(h)
template<int MODE>
__global__ __launch_bounds__(256) void ode_gemm(
    const ushort* __restrict__ A, const ushort* __restrict__ W,
    const float* __restrict__ bias, float* __restrict__ h,
    ushort* __restrict__ Cb)
{
    __shared__ __align__(16) ushort Alds[2][128 * 64];
    __shared__ __align__(16) ushort Blds[2][64 * 64];
    const int tid = threadIdx.x, lane = tid & 63, w = tid >> 6;
    const int wr = w >> 1, wc = w & 1;
    const int r0 = blockIdx.y * 128, c0 = blockIdx.x * 64;
    const int srow = lane >> 3;                       // row within 8-row group
    const int sg   = ((lane & 7) ^ srow) << 3;        // pre-swizzled slot offset

    f32x4 acc[4][2] = {};

    #define STAGE(b, k0) do {                                                   \
        _Pragma("unroll")                                                        \
        for (int i_ = 0; i_ < 4; ++i_) {                                         \
            int rb_ = w * 32 + i_ * 8;                                           \
            gload_lds16(A + (size_t)(r0 + rb_ + srow) * HID + (k0) + sg,         \
                        &Alds[b][rb_ * 64]);                                     \
        }                                                                        \
        _Pragma("unroll")                                                        \
        for (int i_ = 0; i_ < 2; ++i_) {                                         \
            int rb_ = w * 16 + i_ * 8;                                           \
            gload_lds16(W + (size_t)(c0 + rb_ + srow) * HID + (k0) + sg,         \
                        &Blds[b][rb_ * 64]);                                     \
        }                                                                        \
    } while (0)

    STAGE(0, 0);
    __syncthreads();                    // vmcnt(0) drained by compiler
    int cur = 0;
    for (int t = 0; t < HID / 64; ++t) {
        if (t < HID / 64 - 1) STAGE(cur ^ 1, (t + 1) * 64);   // prefetch next
        short8 af[4][2], bf[2][2];
        #pragma unroll
        for (int mi = 0; mi < 4; ++mi) {
            int r = wr * 64 + mi * 16 + (lane & 15);
            #pragma unroll
            for (int ks = 0; ks < 2; ++ks) af[mi][ks] = frag64(&Alds[cur][0], r, ks, lane);
        }
        #pragma unroll
        for (int ni = 0; ni < 2; ++ni) {
            int c = wc * 32 + ni * 16 + (lane & 15);
            #pragma unroll
            for (int ks = 0; ks < 2; ++ks) bf[ni][ks] = frag64(&Blds[cur][0], c, ks, lane);
        }
        #pragma unroll
        for (int ks = 0; ks < 2; ++ks)
            #pragma unroll
            for (int mi = 0; mi < 4; ++mi)
                #pragma unroll
                for (int ni = 0; ni < 2; ++ni)
                    acc[mi][ni] = __builtin_amdgcn_mfma_f32_16x16x32_bf16(
                        af[mi][ks], bf[ni][ks], acc[mi][ni], 0, 0, 0);
        __syncthreads();                // next buffer landed; cur reads done
        cur ^= 1;
    }
    #undef STAGE

    #pragma unroll
    for (int mi = 0; mi < 4; ++mi)
        #pragma unroll
        for (int ni = 0; ni < 2; ++ni) {
            const int c = c0 + wc * 32 + ni * 16 + (lane & 15);
            const float bv = bias[c];
            #pragma unroll
            for (int ii = 0; ii < 4; ++ii) {
                const int r = r0 + wr * 64 + mi * 16 + ((lane >> 4) << 2) + ii;
                const size_t o = (size_t)r * HID + c;
                float v = acc[mi][ni][ii] + bv;
                if (MODE == 0) {
                    Cb[o] = f2bf(tanhf(v));
                } else {
                    float nh = h[o] + DT_C * v;
                    h[o] = nh; Cb[o] = f2bf(nh);
                }
            }
        }
}

// ---------------- event GEMM: A rows gathered from hb[idx], optional K=64 tail
// MODE 0: q = relu(hg Wp1^T + bp1)            -> qb bf16    (no tail)
// MODE 1: rz = sigmoid(concatK + b_ih + b_hh) -> rz fp32    (tail into acc)
// MODE 2: GRU n-gate + combine + scatter to h (tail into accX)
template<int MODE>
__global__ __launch_bounds__(256) void event_gemm(
    const ushort* __restrict__ hb, const ushort* __restrict__ Xbk,
    const int* __restrict__ idx,
    const ushort* __restrict__ Bh, const ushort* __restrict__ Bx,
    const float* __restrict__ bias_i, const float* __restrict__ bias_h,
    float* __restrict__ rz, ushort* __restrict__ qb, float* __restrict__ h)
{
    __shared__ __align__(16) ushort Alds[64 * 64];
    __shared__ __align__(16) ushort Blds[64 * 64];
    const int tid = threadIdx.x, lane = tid & 63, w = tid >> 6;
    const int wr = w >> 1, wc = w & 1;
    const int r0t = blockIdx.y * 64;
    const int c0t = blockIdx.x * 64;

    f32x4 acc[2][2] = {};
    f32x4 accX[2][2] = {};

    const int arow = w * 16 + (lane >> 3);
    const int sg   = ((lane & 7) ^ ((lane >> 3) & 7)) << 3;
    const int gidx0 = idx[r0t + arow];
    const int gidx1 = idx[r0t + arow + 8];

    for (int k0 = 0; k0 < HID; k0 += 64) {
        __syncthreads();
        gload_lds16(hb + (size_t)gidx0 * HID + k0 + sg, &Alds[(w * 16) * 64]);
        gload_lds16(hb + (size_t)gidx1 * HID + k0 + sg, &Alds[(w * 16 + 8) * 64]);
        gload_lds16(Bh + (size_t)(c0t + arow) * HID + k0 + sg, &Blds[(w * 16) * 64]);
        gload_lds16(Bh + (size_t)(c0t + arow + 8) * HID + k0 + sg, &Blds[(w * 16 + 8) * 64]);
        __syncthreads();
        short8 af[2][2], bf[2][2];
        #pragma unroll
        for (int mi = 0; mi < 2; ++mi) {
            int r = wr * 32 + mi * 16 + (lane & 15);
            #pragma unroll
            for (int ks = 0; ks < 2; ++ks) af[mi][ks] = frag64(Alds, r, ks, lane);
        }
        #pragma unroll
        for (int ni = 0; ni < 2; ++ni) {
            int c = wc * 32 + ni * 16 + (lane & 15);
            #pragma unroll
            for (int ks = 0; ks < 2; ++ks) bf[ni][ks] = frag64(Blds, c, ks, lane);
        }
        #pragma unroll
        for (int ks = 0; ks < 2; ++ks)
            #pragma unroll
            for (int mi = 0; mi < 2; ++mi)
                #pragma unroll
                for (int ni = 0; ni < 2; ++ni)
                    acc[mi][ni] = __builtin_amdgcn_mfma_f32_16x16x32_bf16(
                        af[mi][ks], bf[ni][ks], acc[mi][ni], 0, 0, 0);
    }

    if (MODE != 0) {   // K tail: A from Xbk (stride 64), B from Bx (stride 64)
        __syncthreads();
        gload_lds16(Xbk + (size_t)(r0t + arow) * DIM + sg, &Alds[(w * 16) * 64]);
        gload_lds16(Xbk + (size_t)(r0t + arow + 8) * DIM + sg, &Alds[(w * 16 + 8) * 64]);
        gload_lds16(Bx + (size_t)(c0t + arow) * DIM + sg, &Blds[(w * 16) * 64]);
        gload_lds16(Bx + (size_t)(c0t + arow + 8) * DIM + sg, &Blds[(w * 16 + 8) * 64]);
        __syncthreads();
        short8 af[2][2], bf[2][2];
        #pragma unroll
        for (int mi = 0; mi < 2; ++mi) {
            int r = wr * 32 + mi * 16 + (lane & 15);
            #pragma unroll
            for (int ks = 0; ks < 2; ++ks) af[mi][ks] = frag64(Alds, r, ks, lane);
        }
        #pragma unroll
        for (int ni = 0; ni < 2; ++ni) {
            int c = wc * 32 + ni * 16 + (lane & 15);
            #pragma unroll
            for (int ks = 0; ks < 2; ++ks) bf[ni][ks] = frag64(Blds, c, ks, lane);
        }
        #pragma unroll
        for (int ks = 0; ks < 2; ++ks)
            #pragma unroll
            for (int mi = 0; mi < 2; ++mi)
                #pragma unroll
                for (int ni = 0; ni < 2; ++ni) {
                    f32x4& a = (MODE == 2) ? accX[mi][ni] : acc[mi][ni];
                    a = __builtin_amdgcn_mfma_f32_16x16x32_bf16(
                        af[mi][ks], bf[ni][ks], a, 0, 0, 0);
                }
    }

    #pragma unroll
    for (int mi = 0; mi < 2; ++mi)
        #pragma unroll
        for (int ni = 0; ni < 2; ++ni) {
            const int c = c0t + wc * 32 + ni * 16 + (lane & 15);
            #pragma unroll
            for (int ii = 0; ii < 4; ++ii) {
                const int iobs = r0t + wr * 32 + mi * 16 + ((lane >> 4) << 2) + ii;
                float v = acc[mi][ni][ii];
                if (MODE == 0) {
                    qb[(size_t)iobs * HID + c] = f2bf(fmaxf(v + bias_h[c], 0.0f));
                } else if (MODE == 1) {
                    rz[(size_t)iobs * 1024 + c] = sigmoidf_(v + bias_i[c] + bias_h[c]);
                } else {
                    float vh = v + bias_h[c];
                    float vx = accX[mi][ni][ii] + bias_i[c];
                    float r = rz[(size_t)iobs * 1024 + c];
                    float z = rz[(size_t)iobs * 1024 + 512 + c];
                    float n = tanhf(vx + r * vh);
                    size_t o = (size_t)idx[iobs] * HID + c;
                    h[o] = (1.0f - z) * n + z * h[o];
                }
            }
        }
}

// refresh bf16 shadow of updated rows (after MODE 2)
__global__ __launch_bounds__(256) void scatter_b16(
    const float* __restrict__ h, const int* __restrict__ idx, ushort* __restrict__ hb)
{
    int t = blockIdx.x * 256 + threadIdx.x;   // over NPER*HID/8
    int i = t >> 6, j8 = (t & 63) << 3;
    size_t o = (size_t)idx[i] * HID + j8;
    float4 a = *(const float4*)&h[o];
    float4 b = *(const float4*)&h[o + 4];
    ushort ob[8] = {f2bf(a.x), f2bf(a.y), f2bf(a.z), f2bf(a.w),
                    f2bf(b.x), f2bf(b.y), f2bf(b.z), f2bf(b.w)};
    *(ushort4*)&hb[o]     = *(ushort4*)&ob[0];
    *(ushort4*)&hb[o + 4] = *(ushort4*)&ob[4];
}

__device__ __forceinline__ void block_atomic_sum(float v, float* acc) {
    __shared__ float red[4];
    #pragma unroll
    for (int off = 32; off > 0; off >>= 1) v += __shfl_down(v, off);
    int lane = threadIdx.x & 63, wid = threadIdx.x >> 6;
    if (lane == 0) red[wid] = v;
    __syncthreads();
    if (threadIdx.x == 0) atomicAdd(acc, red[0] + red[1] + red[2] + red[3]);
}

// ---------------- p = q Wp2^T + bp2 fused with NLL loss reduce ----------------
__global__ __launch_bounds__(256) void p_loss(
    const ushort* __restrict__ qb, const ushort* __restrict__ Wp2b,
    const float* __restrict__ bp2, const float* __restrict__ Xk,
    const float* __restrict__ Mk, float* __restrict__ loss_acc)
{
    __shared__ __align__(16) ushort Alds[64 * 64];
    __shared__ __align__(16) ushort Blds[128 * 64];
    __shared__ float Plds[64 * 128];
    const int tid = threadIdx.x, lane = tid & 63, w = tid >> 6;
    const int wr = w >> 1, wc = w & 1;
    const int r0t = blockIdx.x * 64;
    const int arow = w * 16 + (lane >> 3);
    const int sg   = ((lane & 7) ^ ((lane >> 3) & 7)) << 3;

    f32x4 acc[2][4] = {};
    for (int k0 = 0; k0 < HID; k0 += 64) {
        __syncthreads();
        gload_lds16(qb + (size_t)(r0t + arow) * HID + k0 + sg, &Alds[(w * 16) * 64]);
        gload_lds16(qb + (size_t)(r0t + arow + 8) * HID + k0 + sg, &Alds[(w * 16 + 8) * 64]);
        #pragma unroll
        for (int j = 0; j < 4; ++j) {
            int g = w * 4 + j;
            int rw = g * 8 + (lane >> 3);
            gload_lds16(Wp2b + (size_t)rw * HID + k0 + (((lane & 7) ^ (rw & 7)) << 3),
                        &Blds[g * 8 * 64]);
        }
        __syncthreads();
        short8 af[2][2], bf[4][2];
        #pragma unroll
        for (int mi = 0; mi < 2; ++mi) {
            int r = wr * 32 + mi * 16 + (lane & 15);
            #pragma unroll
            for (int ks = 0; ks < 2; ++ks) af[mi][ks] = frag64(Alds, r, ks, lane);
        }
        #pragma unroll
        for (int ni = 0; ni < 4; ++ni) {
            int c = wc * 64 + ni * 16 + (lane & 15);
            #pragma unroll
            for (int ks = 0; ks < 2; ++ks) bf[ni][ks] = frag64(Blds, c, ks, lane);
        }
        #pragma unroll
        for (int ks = 0; ks < 2; ++ks)
            #pragma unroll
            for (int mi = 0; mi < 2; ++mi)
                #pragma unroll
                for (int ni = 0; ni < 4; ++ni)
                    acc[mi][ni] = __builtin_amdgcn_mfma_f32_16x16x32_bf16(
                        af[mi][ks], bf[ni][ks], acc[mi][ni], 0, 0, 0);
    }

    #pragma unroll
    for (int mi = 0; mi < 2; ++mi)
        #pragma unroll
        for (int ni = 0; ni < 4; ++ni) {
            int c = wc * 64 + ni * 16 + (lane & 15);
            float bv = bp2[c];
            #pragma unroll
            for (int ii = 0; ii < 4; ++ii) {
                int r = wr * 32 + mi * 16 + ((lane >> 4) << 2) + ii;
                Plds[r * 128 + c] = acc[mi][ni][ii] + bv;
            }
        }
    __syncthreads();

    float local = 0.0f;
    for (int t = tid; t < 64 * 64; t += 256) {
        int r = t >> 6, j = t & 63;
        float mean = Plds[r * 128 + j];
        float lv   = Plds[r * 128 + 64 + j];
        int g = r0t + r;
        float err = (Xk[g * 64 + j] - mean) * expf(-0.5f * lv);
        local += 0.5f * (err * err + lv + 2.0f * LOG_SQRT_2PI_C) * Mk[g * 64 + j];
    }
    block_atomic_sum(local, loss_acc);
}

__global__ __launch_bounds__(256) void f2b4_kernel(
    const float* __restrict__ s, ushort* __restrict__ d, int n4)
{
    int t = blockIdx.x * 256 + threadIdx.x;
    if (t >= n4) return;
    float4 v = ((const float4*)s)[t];
    ushort4 o; o.x = f2bf(v.x); o.y = f2bf(v.y); o.z = f2bf(v.z); o.w = f2bf(v.w);
    ((ushort4*)d)[t] = o;
}

__global__ __launch_bounds__(256) void msum_kernel(
    const float* __restrict__ M, int n, float* __restrict__ m_acc)
{
    float v = 0.0f;
    for (int t = blockIdx.x * 256 + threadIdx.x; t < n; t += gridDim.x * 256)
        v += M[t];
    block_atomic_sum(v, m_acc);
}

__global__ void finalize_kernel(const float* __restrict__ sums, float* __restrict__ out) {
    if (threadIdx.x == 0) { out[0] = sums[0] / sums[1]; out[1] = 0.0f; }
}

extern "C" void kernel_launch(void* const* d_in, const int* in_sizes, int n_in,
                              void* d_out, int out_size, void* d_ws, size_t ws_size,
                              hipStream_t stream) {
    const float* X      = (const float*)d_in[3];
    const float* M      = (const float*)d_in[4];
    const int* batch_idx= (const int*)  d_in[5];
    const float* W_ode1 = (const float*)d_in[6];
    const float* b_ode1 = (const float*)d_in[7];
    const float* W_ode2 = (const float*)d_in[8];
    const float* b_ode2 = (const float*)d_in[9];
    const float* W_ih   = (const float*)d_in[10];
    const float* W_hh   = (const float*)d_in[11];
    const float* b_ih   = (const float*)d_in[12];
    const float* b_hh   = (const float*)d_in[13];
    const float* Wp1    = (const float*)d_in[14];
    const float* bp1    = (const float*)d_in[15];
    const float* Wp2    = (const float*)d_in[16];
    const float* bp2    = (const float*)d_in[17];
    float* out = (float*)d_out;

    float* ws   = (float*)d_ws;
    float* h    = ws;                                   // 4096*512
    float* rz   = h  + (size_t)BATCH * HID;             // 2048*1024
    float* sums = rz + (size_t)NPER * 1024;             // 16
    ushort* hb   = (ushort*)(sums + 16);                // 4096*512
    ushort* tbb  = hb   + (size_t)BATCH * HID;          // 4096*512
    ushort* qb   = tbb  + (size_t)BATCH * HID;          // 2048*512
    ushort* Xb   = qb   + (size_t)NPER * HID;           // 25*2048*64
    ushort* W1b  = Xb   + (size_t)KEV * NPER * DIM;     // 512*512
    ushort* W2b  = W1b  + (size_t)HID * HID;
    ushort* Wp1b = W2b  + (size_t)HID * HID;
    ushort* Wp2b = Wp1b + (size_t)HID * HID;            // 128*512
    ushort* Wihb = Wp2b + (size_t)2 * DIM * HID;        // 1536*64
    ushort* Whhb = Wihb + (size_t)(3 * HID) * DIM;      // 1536*512

    hipMemsetAsync(h,    0, (size_t)BATCH * HID * sizeof(float), stream);
    hipMemsetAsync(hb,   0, (size_t)BATCH * HID * sizeof(ushort), stream);
    hipMemsetAsync(sums, 0, 2 * sizeof(float), stream);

    dim3 blk(256);
    auto cvt = [&](const float* s, ushort* d, size_t n) {
        f2b4_kernel<<<dim3((unsigned)((n / 4 + 255) / 256)), blk, 0, stream>>>(s, d, (int)(n / 4));
    };
    cvt(W_ode1, W1b,  (size_t)HID * HID);
    cvt(W_ode2, W2b,  (size_t)HID * HID);
    cvt(Wp1,    Wp1b, (size_t)HID * HID);
    cvt(Wp2,    Wp2b, (size_t)2 * DIM * HID);
    cvt(W_ih,   Wihb, (size_t)3 * HID * DIM);
    cvt(W_hh,   Whhb, (size_t)3 * HID * HID);
    cvt(X,      Xb,   (size_t)KEV * NPER * DIM);

    msum_kernel<<<1024, blk, 0, stream>>>(M, KEV * NPER * DIM, sums + 1);

    dim3 gOde(HID / 64, BATCH / 128);   // (8, 32) = 256 blocks

    for (int k = 0; k < KEV; ++k) {
        const float*  Xk  = X  + (size_t)k * NPER * DIM;
        const float*  Mk  = M  + (size_t)k * NPER * DIM;
        const ushort* Xbk = Xb + (size_t)k * NPER * DIM;
        const int*   idxk = batch_idx + (size_t)k * NPER;

        for (int s = 0; s < 2; ++s) {
            ode_gemm<0><<<gOde, blk, 0, stream>>>(hb,  W1b, b_ode1, nullptr, tbb);
            ode_gemm<1><<<gOde, blk, 0, stream>>>(tbb, W2b, b_ode2, h,       hb);
        }

        // head: q = relu(hg Wp1^T + bp1); then p+loss fused
        event_gemm<0><<<dim3(8, 32), blk, 0, stream>>>(
            hb, nullptr, idxk, Wp1b, nullptr, nullptr, bp1, nullptr, qb, nullptr);
        p_loss<<<32, blk, 0, stream>>>(qb, Wp2b, bp2, Xk, Mk, sums);

        // GRU: rz (concat-K), then n-gate + combine + scatter, then bf16 refresh
        event_gemm<1><<<dim3(16, 32), blk, 0, stream>>>(
            hb, Xbk, idxk, Whhb, Wihb, b_ih, b_hh, rz, nullptr, nullptr);
        event_gemm<2><<<dim3(8, 32), blk, 0, stream>>>(
            hb, Xbk, idxk, Whhb + (size_t)1024 * HID, Wihb + (size_t)1024 * DIM,
            b_ih + 1024, b_hh + 1024, rz, nullptr, h);
        scatter_b16<<<NPER * HID / 8 / 256, blk, 0, stream>>>(h, idxk, hb);
    }

    finalize_kernel<<<1, 64, 0, stream>>>(sums, out);
}

// Round 5
// 2490.660 us; speedup vs baseline: 1.3644x; 1.1495x over previous
//
#include <hip/hip_runtime.h>
#include <cstdint>
#include <cstddef>

#define BATCH 4096
#define DIM 64
#define HID 512
#define NPER 2048
#define KEV 25
#define DT_C 0.01f
#define LOG_SQRT_2PI_C 0.9189385332046727f

typedef __attribute__((ext_vector_type(8))) short short8;
typedef __attribute__((ext_vector_type(4))) float f32x4;

__device__ __forceinline__ ushort f2bf(float f) {
    uint32_t u = __float_as_uint(f);
    u += 0x7FFF + ((u >> 16) & 1);
    return (ushort)(u >> 16);
}
__device__ __forceinline__ float sigmoidf_(float x) { return 1.0f / (1.0f + expf(-x)); }

__device__ __forceinline__ void gload_lds16(const ushort* g, ushort* l) {
    __builtin_amdgcn_global_load_lds(
        (const __attribute__((address_space(1))) void*)g,
        (__attribute__((address_space(3))) void*)l, 16, 0, 0);
}

// A-fragment from a [rows][64] LDS tile, XOR-swizzled in 8-elem slots
__device__ __forceinline__ short8 frag64(const ushort* lds, int row, int ks, int lane) {
    int slot = ((ks << 2) + (lane >> 4)) ^ (row & 7);
    return *(const short8*)&lds[row * 64 + slot * 8];
}
// B-fragment direct from global (row-major weights, leading dim ldb)
__device__ __forceinline__ short8 bglob(const ushort* B, int col, int ldb, int k0, int ks, int lane) {
    int slot = (ks << 2) + (lane >> 4);
    return *(const short8*)&B[(size_t)col * ldb + k0 + slot * 8];
}

// ---------------- ODE GEMM: 64x64 tile, A dbuf-LDS, B direct-global ----------
// MODE 0: Cb = bf16(tanh(v + bias))
// MODE 1: h += DT*(v + bias) (fp32 master), Cb = bf16(h)
template<int MODE>
__global__ __launch_bounds__(256) void ode_gemm(
    const ushort* __restrict__ A, const ushort* __restrict__ W,
    const float* __restrict__ bias, float* __restrict__ h, ushort* __restrict__ Cb)
{
    __shared__ __align__(16) ushort Alds[2][64 * 64];
    const int tid = threadIdx.x, lane = tid & 63, w = tid >> 6;
    const int wr = w >> 1, wc = w & 1;
    // XCD-aware mapping: XCD x owns row-strips [x*8, x*8+8) x all 8 col-strips
    const int raw = blockIdx.x;
    const int xcd = raw & 7, j = raw >> 3;
    const int r0 = ((xcd << 3) + (j >> 3)) << 6;
    const int c0 = (j & 7) << 6;

    const int srow = lane >> 3;
    const int sg = ((lane & 7) ^ srow) << 3;
    const size_t gr0 = (size_t)(r0 + w * 16 + srow) * HID;
    const size_t gr1 = (size_t)(r0 + w * 16 + 8 + srow) * HID;

    f32x4 acc[2][2] = {};
    const int bc0 = c0 + wc * 32 + (lane & 15);
    short8 bcur[2][2], bnxt[2][2];

    gload_lds16(A + gr0 + sg, &Alds[0][(w * 16) * 64]);
    gload_lds16(A + gr1 + sg, &Alds[0][(w * 16 + 8) * 64]);
    #pragma unroll
    for (int ni = 0; ni < 2; ++ni)
        #pragma unroll
        for (int ks = 0; ks < 2; ++ks)
            bcur[ni][ks] = bglob(W, bc0 + ni * 16, HID, 0, ks, lane);
    __syncthreads();

    int cur = 0;
    for (int t = 0; t < HID / 64; ++t) {
        if (t < HID / 64 - 1) {
            const int kn = (t + 1) * 64;
            gload_lds16(A + gr0 + kn + sg, &Alds[cur ^ 1][(w * 16) * 64]);
            gload_lds16(A + gr1 + kn + sg, &Alds[cur ^ 1][(w * 16 + 8) * 64]);
            #pragma unroll
            for (int ni = 0; ni < 2; ++ni)
                #pragma unroll
                for (int ks = 0; ks < 2; ++ks)
                    bnxt[ni][ks] = bglob(W, bc0 + ni * 16, HID, kn, ks, lane);
        }
        short8 af[2][2];
        #pragma unroll
        for (int mi = 0; mi < 2; ++mi) {
            int r = wr * 32 + mi * 16 + (lane & 15);
            #pragma unroll
            for (int ks = 0; ks < 2; ++ks) af[mi][ks] = frag64(&Alds[cur][0], r, ks, lane);
        }
        #pragma unroll
        for (int ks = 0; ks < 2; ++ks)
            #pragma unroll
            for (int mi = 0; mi < 2; ++mi)
                #pragma unroll
                for (int ni = 0; ni < 2; ++ni)
                    acc[mi][ni] = __builtin_amdgcn_mfma_f32_16x16x32_bf16(
                        af[mi][ks], bcur[ni][ks], acc[mi][ni], 0, 0, 0);
        __syncthreads();
        #pragma unroll
        for (int ni = 0; ni < 2; ++ni)
            #pragma unroll
            for (int ks = 0; ks < 2; ++ks) bcur[ni][ks] = bnxt[ni][ks];
        cur ^= 1;
    }

    #pragma unroll
    for (int mi = 0; mi < 2; ++mi)
        #pragma unroll
        for (int ni = 0; ni < 2; ++ni) {
            const int c = c0 + wc * 32 + ni * 16 + (lane & 15);
            const float bv = bias[c];
            #pragma unroll
            for (int ii = 0; ii < 4; ++ii) {
                const int r = r0 + wr * 32 + mi * 16 + ((lane >> 4) << 2) + ii;
                const size_t o = (size_t)r * HID + c;
                float v = acc[mi][ni][ii] + bv;
                if (MODE == 0) {
                    Cb[o] = f2bf(tanhf(v));
                } else {
                    float nh = h[o] + DT_C * v;
                    h[o] = nh; Cb[o] = f2bf(nh);
                }
            }
        }
}

// ---------------- event kernel 1: q (x<8) and rz (x>=8), merged --------------
__global__ __launch_bounds__(256) void event_k1(
    const ushort* __restrict__ hb, const ushort* __restrict__ Xbk,
    const int* __restrict__ idx,
    const ushort* __restrict__ Wp1b, const float* __restrict__ bp1,
    const ushort* __restrict__ Whhb, const ushort* __restrict__ Wihb,
    const float* __restrict__ b_ih, const float* __restrict__ b_hh,
    ushort* __restrict__ qb, float* __restrict__ rz)
{
    __shared__ __align__(16) ushort Alds[2][64 * 64];
    const int tid = threadIdx.x, lane = tid & 63, w = tid >> 6;
    const int wr = w >> 1, wc = w & 1;
    const bool isQ = blockIdx.x < 8;
    const int c0 = (isQ ? blockIdx.x : (blockIdx.x - 8)) * 64;
    const int r0t = blockIdx.y * 64;
    const ushort* Bw = isQ ? Wp1b : Whhb;

    const int srow = lane >> 3;
    const int sg = ((lane & 7) ^ srow) << 3;
    const int sr0 = w * 16 + srow, sr1 = w * 16 + 8 + srow;
    const size_t ga0 = (size_t)idx[r0t + sr0] * HID;
    const size_t ga1 = (size_t)idx[r0t + sr1] * HID;

    f32x4 acc[2][2] = {};
    const int bc0 = c0 + wc * 32 + (lane & 15);
    short8 bcur[2][2], bnxt[2][2];

    gload_lds16(hb + ga0 + sg, &Alds[0][(w * 16) * 64]);
    gload_lds16(hb + ga1 + sg, &Alds[0][(w * 16 + 8) * 64]);
    #pragma unroll
    for (int ni = 0; ni < 2; ++ni)
        #pragma unroll
        for (int ks = 0; ks < 2; ++ks)
            bcur[ni][ks] = bglob(Bw, bc0 + ni * 16, HID, 0, ks, lane);
    __syncthreads();

    int cur = 0;
    for (int t = 0; t < HID / 64; ++t) {
        if (t < HID / 64 - 1) {
            const int kn = (t + 1) * 64;
            gload_lds16(hb + ga0 + kn + sg, &Alds[cur ^ 1][(w * 16) * 64]);
            gload_lds16(hb + ga1 + kn + sg, &Alds[cur ^ 1][(w * 16 + 8) * 64]);
            #pragma unroll
            for (int ni = 0; ni < 2; ++ni)
                #pragma unroll
                for (int ks = 0; ks < 2; ++ks)
                    bnxt[ni][ks] = bglob(Bw, bc0 + ni * 16, HID, kn, ks, lane);
        }
        short8 af[2][2];
        #pragma unroll
        for (int mi = 0; mi < 2; ++mi) {
            int r = wr * 32 + mi * 16 + (lane & 15);
            #pragma unroll
            for (int ks = 0; ks < 2; ++ks) af[mi][ks] = frag64(&Alds[cur][0], r, ks, lane);
        }
        #pragma unroll
        for (int ks = 0; ks < 2; ++ks)
            #pragma unroll
            for (int mi = 0; mi < 2; ++mi)
                #pragma unroll
                for (int ni = 0; ni < 2; ++ni)
                    acc[mi][ni] = __builtin_amdgcn_mfma_f32_16x16x32_bf16(
                        af[mi][ks], bcur[ni][ks], acc[mi][ni], 0, 0, 0);
        __syncthreads();
        #pragma unroll
        for (int ni = 0; ni < 2; ++ni)
            #pragma unroll
            for (int ks = 0; ks < 2; ++ks) bcur[ni][ks] = bnxt[ni][ks];
        cur ^= 1;
    }

    if (!isQ) {   // K tail: A = Xbk rows (obs-indexed), B = Wihb, K=64
        gload_lds16(Xbk + (size_t)(r0t + sr0) * DIM + sg, &Alds[0][(w * 16) * 64]);
        gload_lds16(Xbk + (size_t)(r0t + sr1) * DIM + sg, &Alds[0][(w * 16 + 8) * 64]);
        short8 bt[2][2];
        #pragma unroll
        for (int ni = 0; ni < 2; ++ni)
            #pragma unroll
            for (int ks = 0; ks < 2; ++ks)
                bt[ni][ks] = bglob(Wihb, bc0 + ni * 16, DIM, 0, ks, lane);
        __syncthreads();
        short8 af[2][2];
        #pragma unroll
        for (int mi = 0; mi < 2; ++mi) {
            int r = wr * 32 + mi * 16 + (lane & 15);
            #pragma unroll
            for (int ks = 0; ks < 2; ++ks) af[mi][ks] = frag64(&Alds[0][0], r, ks, lane);
        }
        #pragma unroll
        for (int ks = 0; ks < 2; ++ks)
            #pragma unroll
            for (int mi = 0; mi < 2; ++mi)
                #pragma unroll
                for (int ni = 0; ni < 2; ++ni)
                    acc[mi][ni] = __builtin_amdgcn_mfma_f32_16x16x32_bf16(
                        af[mi][ks], bt[ni][ks], acc[mi][ni], 0, 0, 0);
    }

    #pragma unroll
    for (int mi = 0; mi < 2; ++mi)
        #pragma unroll
        for (int ni = 0; ni < 2; ++ni) {
            const int c = c0 + wc * 32 + ni * 16 + (lane & 15);
            #pragma unroll
            for (int ii = 0; ii < 4; ++ii) {
                const int iobs = r0t + wr * 32 + mi * 16 + ((lane >> 4) << 2) + ii;
                float v = acc[mi][ni][ii];
                if (isQ) qb[(size_t)iobs * HID + c] = f2bf(fmaxf(v + bp1[c], 0.0f));
                else     rz[(size_t)iobs * 1024 + c] = sigmoidf_(v + b_ih[c] + b_hh[c]);
            }
        }
}

__device__ __forceinline__ void block_atomic_sum(float v, float* acc) {
    __shared__ float red[4];
    #pragma unroll
    for (int off = 32; off > 0; off >>= 1) v += __shfl_down(v, off);
    int lane = threadIdx.x & 63, wid = threadIdx.x >> 6;
    if (lane == 0) red[wid] = v;
    __syncthreads();
    if (threadIdx.x == 0) atomicAdd(acc, red[0] + red[1] + red[2] + red[3]);
}

// ---------------- event kernel 2: n-gate+scatter (x<8) and p+loss (x==8) -----
__global__ __launch_bounds__(256) void event_k2(
    const ushort* __restrict__ hb, const ushort* __restrict__ Xbk,
    const int* __restrict__ idx,
    const ushort* __restrict__ Whh_n, const ushort* __restrict__ Wih_n,
    const float* __restrict__ bi_n, const float* __restrict__ bh_n,
    const float* __restrict__ rz, float* __restrict__ h,
    const ushort* __restrict__ qb, const ushort* __restrict__ Wp2b,
    const float* __restrict__ bp2, const float* __restrict__ Xk,
    const float* __restrict__ Mk, float* __restrict__ loss_acc)
{
    __shared__ __align__(16) ushort Alds[2][64 * 64];
    __shared__ float Plds[64 * 128];
    const int tid = threadIdx.x, lane = tid & 63, w = tid >> 6;
    const int wr = w >> 1, wc = w & 1;
    const int r0t = blockIdx.y * 64;
    const int srow = lane >> 3;
    const int sg = ((lane & 7) ^ srow) << 3;
    const int sr0 = w * 16 + srow, sr1 = w * 16 + 8 + srow;

    if (blockIdx.x < 8) {
        // ---- n-gate ----
        const int c0 = blockIdx.x * 64;
        const size_t ga0 = (size_t)idx[r0t + sr0] * HID;
        const size_t ga1 = (size_t)idx[r0t + sr1] * HID;
        f32x4 acc[2][2] = {}, accX[2][2] = {};
        const int bc0 = c0 + wc * 32 + (lane & 15);
        short8 bcur[2][2], bnxt[2][2];

        gload_lds16(hb + ga0 + sg, &Alds[0][(w * 16) * 64]);
        gload_lds16(hb + ga1 + sg, &Alds[0][(w * 16 + 8) * 64]);
        #pragma unroll
        for (int ni = 0; ni < 2; ++ni)
            #pragma unroll
            for (int ks = 0; ks < 2; ++ks)
                bcur[ni][ks] = bglob(Whh_n, bc0 + ni * 16, HID, 0, ks, lane);
        __syncthreads();

        int cur = 0;
        for (int t = 0; t < HID / 64; ++t) {
            if (t < HID / 64 - 1) {
                const int kn = (t + 1) * 64;
                gload_lds16(hb + ga0 + kn + sg, &Alds[cur ^ 1][(w * 16) * 64]);
                gload_lds16(hb + ga1 + kn + sg, &Alds[cur ^ 1][(w * 16 + 8) * 64]);
                #pragma unroll
                for (int ni = 0; ni < 2; ++ni)
                    #pragma unroll
                    for (int ks = 0; ks < 2; ++ks)
                        bnxt[ni][ks] = bglob(Whh_n, bc0 + ni * 16, HID, kn, ks, lane);
            }
            short8 af[2][2];
            #pragma unroll
            for (int mi = 0; mi < 2; ++mi) {
                int r = wr * 32 + mi * 16 + (lane & 15);
                #pragma unroll
                for (int ks = 0; ks < 2; ++ks) af[mi][ks] = frag64(&Alds[cur][0], r, ks, lane);
            }
            #pragma unroll
            for (int ks = 0; ks < 2; ++ks)
                #pragma unroll
                for (int mi = 0; mi < 2; ++mi)
                    #pragma unroll
                    for (int ni = 0; ni < 2; ++ni)
                        acc[mi][ni] = __builtin_amdgcn_mfma_f32_16x16x32_bf16(
                            af[mi][ks], bcur[ni][ks], acc[mi][ni], 0, 0, 0);
            __syncthreads();
            #pragma unroll
            for (int ni = 0; ni < 2; ++ni)
                #pragma unroll
                for (int ks = 0; ks < 2; ++ks) bcur[ni][ks] = bnxt[ni][ks];
            cur ^= 1;
        }
        // tail from X
        gload_lds16(Xbk + (size_t)(r0t + sr0) * DIM + sg, &Alds[0][(w * 16) * 64]);
        gload_lds16(Xbk + (size_t)(r0t + sr1) * DIM + sg, &Alds[0][(w * 16 + 8) * 64]);
        short8 bt[2][2];
        #pragma unroll
        for (int ni = 0; ni < 2; ++ni)
            #pragma unroll
            for (int ks = 0; ks < 2; ++ks)
                bt[ni][ks] = bglob(Wih_n, bc0 + ni * 16, DIM, 0, ks, lane);
        __syncthreads();
        short8 af[2][2];
        #pragma unroll
        for (int mi = 0; mi < 2; ++mi) {
            int r = wr * 32 + mi * 16 + (lane & 15);
            #pragma unroll
            for (int ks = 0; ks < 2; ++ks) af[mi][ks] = frag64(&Alds[0][0], r, ks, lane);
        }
        #pragma unroll
        for (int ks = 0; ks < 2; ++ks)
            #pragma unroll
            for (int mi = 0; mi < 2; ++mi)
                #pragma unroll
                for (int ni = 0; ni < 2; ++ni)
                    accX[mi][ni] = __builtin_amdgcn_mfma_f32_16x16x32_bf16(
                        af[mi][ks], bt[ni][ks], accX[mi][ni], 0, 0, 0);

        #pragma unroll
        for (int mi = 0; mi < 2; ++mi)
            #pragma unroll
            for (int ni = 0; ni < 2; ++ni) {
                const int c = c0 + wc * 32 + ni * 16 + (lane & 15);
                #pragma unroll
                for (int ii = 0; ii < 4; ++ii) {
                    const int iobs = r0t + wr * 32 + mi * 16 + ((lane >> 4) << 2) + ii;
                    float vh = acc[mi][ni][ii] + bh_n[c];
                    float vx = accX[mi][ni][ii] + bi_n[c];
                    float r = rz[(size_t)iobs * 1024 + c];
                    float z = rz[(size_t)iobs * 1024 + 512 + c];
                    float n = tanhf(vx + r * vh);
                    size_t o = (size_t)idx[iobs] * HID + c;
                    h[o] = (1.0f - z) * n + z * h[o];
                }
            }
    } else {
        // ---- p = q Wp2^T + bp2, fused NLL loss ----
        f32x4 acc[2][4] = {};
        const int bc0 = wc * 64 + (lane & 15);
        short8 bcur[4][2], bnxt[4][2];

        gload_lds16(qb + (size_t)(r0t + sr0) * HID + sg, &Alds[0][(w * 16) * 64]);
        gload_lds16(qb + (size_t)(r0t + sr1) * HID + sg, &Alds[0][(w * 16 + 8) * 64]);
        #pragma unroll
        for (int ni = 0; ni < 4; ++ni)
            #pragma unroll
            for (int ks = 0; ks < 2; ++ks)
                bcur[ni][ks] = bglob(Wp2b, bc0 + ni * 16, HID, 0, ks, lane);
        __syncthreads();

        int cur = 0;
        for (int t = 0; t < HID / 64; ++t) {
            if (t < HID / 64 - 1) {
                const int kn = (t + 1) * 64;
                gload_lds16(qb + (size_t)(r0t + sr0) * HID + kn + sg, &Alds[cur ^ 1][(w * 16) * 64]);
                gload_lds16(qb + (size_t)(r0t + sr1) * HID + kn + sg, &Alds[cur ^ 1][(w * 16 + 8) * 64]);
                #pragma unroll
                for (int ni = 0; ni < 4; ++ni)
                    #pragma unroll
                    for (int ks = 0; ks < 2; ++ks)
                        bnxt[ni][ks] = bglob(Wp2b, bc0 + ni * 16, HID, kn, ks, lane);
            }
            short8 af[2][2];
            #pragma unroll
            for (int mi = 0; mi < 2; ++mi) {
                int r = wr * 32 + mi * 16 + (lane & 15);
                #pragma unroll
                for (int ks = 0; ks < 2; ++ks) af[mi][ks] = frag64(&Alds[cur][0], r, ks, lane);
            }
            #pragma unroll
            for (int ks = 0; ks < 2; ++ks)
                #pragma unroll
                for (int mi = 0; mi < 2; ++mi)
                    #pragma unroll
                    for (int ni = 0; ni < 4; ++ni)
                        acc[mi][ni] = __builtin_amdgcn_mfma_f32_16x16x32_bf16(
                            af[mi][ks], bcur[ni][ks], acc[mi][ni], 0, 0, 0);
            __syncthreads();
            #pragma unroll
            for (int ni = 0; ni < 4; ++ni)
                #pragma unroll
                for (int ks = 0; ks < 2; ++ks) bcur[ni][ks] = bnxt[ni][ks];
            cur ^= 1;
        }

        #pragma unroll
        for (int mi = 0; mi < 2; ++mi)
            #pragma unroll
            for (int ni = 0; ni < 4; ++ni) {
                int c = wc * 64 + ni * 16 + (lane & 15);
                float bv = bp2[c];
                #pragma unroll
                for (int ii = 0; ii < 4; ++ii) {
                    int r = wr * 32 + mi * 16 + ((lane >> 4) << 2) + ii;
                    Plds[r * 128 + c] = acc[mi][ni][ii] + bv;
                }
            }
        __syncthreads();

        float local = 0.0f;
        for (int t = tid; t < 64 * 64; t += 256) {
            int r = t >> 6, jj = t & 63;
            float mean = Plds[r * 128 + jj];
            float lv   = Plds[r * 128 + 64 + jj];
            int g = r0t + r;
            float err = (Xk[g * 64 + jj] - mean) * expf(-0.5f * lv);
            local += 0.5f * (err * err + lv + 2.0f * LOG_SQRT_2PI_C) * Mk[g * 64 + jj];
        }
        block_atomic_sum(local, loss_acc);
    }
}

// refresh bf16 shadow of GRU-updated rows
__global__ __launch_bounds__(256) void scatter_b16(
    const float* __restrict__ h, const int* __restrict__ idx, ushort* __restrict__ hb)
{
    int t = blockIdx.x * 256 + threadIdx.x;   // over NPER*HID/8
    int i = t >> 6, j8 = (t & 63) << 3;
    size_t o = (size_t)idx[i] * HID + j8;
    float4 a = *(const float4*)&h[o];
    float4 b = *(const float4*)&h[o + 4];
    ushort ob[8] = {f2bf(a.x), f2bf(a.y), f2bf(a.z), f2bf(a.w),
                    f2bf(b.x), f2bf(b.y), f2bf(b.z), f2bf(b.w)};
    *(ushort4*)&hb[o]     = *(ushort4*)&ob[0];
    *(ushort4*)&hb[o + 4] = *(ushort4*)&ob[4];
}

__global__ __launch_bounds__(256) void f2b4_kernel(
    const float* __restrict__ s, ushort* __restrict__ d, int n4)
{
    int t = blockIdx.x * 256 + threadIdx.x;
    if (t >= n4) return;
    float4 v = ((const float4*)s)[t];
    ushort4 o; o.x = f2bf(v.x); o.y = f2bf(v.y); o.z = f2bf(v.z); o.w = f2bf(v.w);
    ((ushort4*)d)[t] = o;
}

__global__ __launch_bounds__(256) void msum_kernel(
    const float* __restrict__ M, int n, float* __restrict__ m_acc)
{
    float v = 0.0f;
    for (int t = blockIdx.x * 256 + threadIdx.x; t < n; t += gridDim.x * 256)
        v += M[t];
    block_atomic_sum(v, m_acc);
}

__global__ void finalize_kernel(const float* __restrict__ sums, float* __restrict__ out) {
    if (threadIdx.x == 0) { out[0] = sums[0] / sums[1]; out[1] = 0.0f; }
}

extern "C" void kernel_launch(void* const* d_in, const int* in_sizes, int n_in,
                              void* d_out, int out_size, void* d_ws, size_t ws_size,
                              hipStream_t stream) {
    const float* X      = (const float*)d_in[3];
    const float* M      = (const float*)d_in[4];
    const int* batch_idx= (const int*)  d_in[5];
    const float* W_ode1 = (const float*)d_in[6];
    const float* b_ode1 = (const float*)d_in[7];
    const float* W_ode2 = (const float*)d_in[8];
    const float* b_ode2 = (const float*)d_in[9];
    const float* W_ih   = (const float*)d_in[10];
    const float* W_hh   = (const float*)d_in[11];
    const float* b_ih   = (const float*)d_in[12];
    const float* b_hh   = (const float*)d_in[13];
    const float* Wp1    = (const float*)d_in[14];
    const float* bp1    = (const float*)d_in[15];
    const float* Wp2    = (const float*)d_in[16];
    const float* bp2    = (const float*)d_in[17];
    float* out = (float*)d_out;

    float* ws   = (float*)d_ws;
    float* h    = ws;                                   // 4096*512
    float* rz   = h  + (size_t)BATCH * HID;             // 2048*1024
    float* sums = rz + (size_t)NPER * 1024;             // 16
    ushort* hb   = (ushort*)(sums + 16);                // 4096*512
    ushort* tbb  = hb   + (size_t)BATCH * HID;          // 4096*512
    ushort* qb   = tbb  + (size_t)BATCH * HID;          // 2048*512
    ushort* Xb   = qb   + (size_t)NPER * HID;           // 25*2048*64
    ushort* W1b  = Xb   + (size_t)KEV * NPER * DIM;     // 512*512
    ushort* W2b  = W1b  + (size_t)HID * HID;
    ushort* Wp1b = W2b  + (size_t)HID * HID;
    ushort* Wp2b = Wp1b + (size_t)HID * HID;            // 128*512
    ushort* Wihb = Wp2b + (size_t)2 * DIM * HID;        // 1536*64
    ushort* Whhb = Wihb + (size_t)(3 * HID) * DIM;      // 1536*512

    hipMemsetAsync(h,    0, (size_t)BATCH * HID * sizeof(float), stream);
    hipMemsetAsync(hb,   0, (size_t)BATCH * HID * sizeof(ushort), stream);
    hipMemsetAsync(sums, 0, 2 * sizeof(float), stream);

    dim3 blk(256);
    auto cvt = [&](const float* s, ushort* d, size_t n) {
        f2b4_kernel<<<dim3((unsigned)((n / 4 + 255) / 256)), blk, 0, stream>>>(s, d, (int)(n / 4));
    };
    cvt(W_ode1, W1b,  (size_t)HID * HID);
    cvt(W_ode2, W2b,  (size_t)HID * HID);
    cvt(Wp1,    Wp1b, (size_t)HID * HID);
    cvt(Wp2,    Wp2b, (size_t)2 * DIM * HID);
    cvt(W_ih,   Wihb, (size_t)3 * HID * DIM);
    cvt(W_hh,   Whhb, (size_t)3 * HID * HID);
    cvt(X,      Xb,   (size_t)KEV * NPER * DIM);

    msum_kernel<<<1024, blk, 0, stream>>>(M, KEV * NPER * DIM, sums + 1);

    for (int k = 0; k < KEV; ++k) {
        const float*  Xk  = X  + (size_t)k * NPER * DIM;
        const float*  Mk  = M  + (size_t)k * NPER * DIM;
        const ushort* Xbk = Xb + (size_t)k * NPER * DIM;
        const int*   idxk = batch_idx + (size_t)k * NPER;

        for (int s = 0; s < 2; ++s) {
            ode_gemm<0><<<512, blk, 0, stream>>>(hb,  W1b, b_ode1, nullptr, tbb);
            ode_gemm<1><<<512, blk, 0, stream>>>(tbb, W2b, b_ode2, h,       hb);
        }

        event_k1<<<dim3(24, 32), blk, 0, stream>>>(
            hb, Xbk, idxk, Wp1b, bp1, Whhb, Wihb, b_ih, b_hh, qb, rz);

        event_k2<<<dim3(9, 32), blk, 0, stream>>>(
            hb, Xbk, idxk,
            Whhb + (size_t)1024 * HID, Wihb + (size_t)1024 * DIM,
            b_ih + 1024, b_hh + 1024, rz, h,
            qb, Wp2b, bp2, Xk, Mk, sums);

        scatter_b16<<<NPER * HID / 8 / 256, blk, 0, stream>>>(h, idxk, hb);
    }

    finalize_kernel<<<1, 64, 0, stream>>>(sums, out);
}